// Round 7
// baseline (185.518 us; speedup 1.0000x reference)
//
#include <hip/hip_runtime.h>
#include <hip/hip_bf16.h>

typedef unsigned short ushort_t;
typedef __attribute__((ext_vector_type(8))) short short8;
typedef __attribute__((ext_vector_type(4))) float f32x4;

constexpr int B  = 2;
constexpr int T  = 2048;
constexpr int E  = 768;
constexpr int H  = 12;
constexpr int HD = 64;

__device__ __forceinline__ ushort_t f2bf(float x) {
  unsigned int u = __float_as_uint(x);
  u += 0x7fffu + ((u >> 16) & 1u);
  return (ushort_t)(u >> 16);
}

__device__ __forceinline__ unsigned int pack_bf2(float a, float b) {
  __hip_bfloat162 h = __float22bfloat162_rn(float2{a, b});
  return *(unsigned int*)&h;
}

// XOR-swizzled LDS index, 64-ushort rows: 16B chunks, chunk ^= row&7.
__device__ __forceinline__ int swz(int row, int col) {
  return row * 64 + ((((col >> 3) ^ (row & 7)) << 3) | (col & 7));
}

// ---------------------------------------------------------------------------
// Fused: fp32->bf16 convert for X + 4 weights, AND fp32 cos/sin rope tables.
// ---------------------------------------------------------------------------
__global__ __launch_bounds__(256) void cvt_all(
    const float* __restrict__ X,  const float* __restrict__ Wq,
    const float* __restrict__ Wk, const float* __restrict__ Wv,
    const float* __restrict__ Wo, const float* __restrict__ rope,
    ushort_t* __restrict__ Xb,  ushort_t* __restrict__ Wqb,
    ushort_t* __restrict__ Wkb, ushort_t* __restrict__ Wvb,
    ushort_t* __restrict__ Wob, float* __restrict__ ct, float* __restrict__ st)
{
  constexpr int NX4 = (B * T * E) / 4;
  constexpr int NW4 = (E * E) / 4;
  constexpr int NC4 = NX4 + 4 * NW4;
  int i = blockIdx.x * 256 + threadIdx.x;
  if (i < NC4) {
    const float* s; ushort_t* d; int j;
    if (i < NX4) { s = X; d = Xb; j = i; }
    else {
      int t = i - NX4;
      int w = t / NW4; j = t - w * NW4;
      s = (w == 0) ? Wq : (w == 1) ? Wk : (w == 2) ? Wv : Wo;
      d = (w == 0) ? Wqb : (w == 1) ? Wkb : (w == 2) ? Wvb : Wob;
    }
    float4 v = ((const float4*)s)[j];
    ushort4 o;
    o.x = f2bf(v.x); o.y = f2bf(v.y); o.z = f2bf(v.z); o.w = f2bf(v.w);
    ((ushort4*)d)[j] = o;
  } else {
    int j = (i - NC4) * 4;
    float4 f = *(const float4*)(rope + j);
    float c, s;
    sincosf(f.x, &s, &c); ct[j+0] = c; st[j+0] = s;
    sincosf(f.y, &s, &c); ct[j+1] = c; st[j+1] = s;
    sincosf(f.z, &s, &c); ct[j+2] = c; st[j+2] = s;
    sincosf(f.w, &s, &c); ct[j+3] = c; st[j+3] = s;
  }
}

// ---------------------------------------------------------------------------
// QKV projection, bf16 MFMA. Tile 128(M)x64(N=one head), K-step 64 (12 iters,
// half the barriers of BK=32). Rotary via tables. Epilogue writes MFMA
// FRAGMENT-ORDER global layouts consumed directly by attn:
//   Qf: per bh, per 16-q group: [kh:2][lane:64][8]  (B-frag, n=q)
//   Kf: per bh, per 64-k tile:  [mt:4][kh:2][lane:64][8]  (A-frag, m=kc)
//   Vf: per bh, per 64-k tile:  [nt:4][kh:2][lane:64][8]  (B-frag, n=d)
// ---------------------------------------------------------------------------
__global__ __launch_bounds__(256) void qkv_gemm(
    const ushort_t* __restrict__ Xb,
    const ushort_t* __restrict__ Wqb, const ushort_t* __restrict__ Wkb,
    const ushort_t* __restrict__ Wvb,
    const float* __restrict__ ct, const float* __restrict__ st,
    ushort_t* __restrict__ qfb, ushort_t* __restrict__ kfb, ushort_t* __restrict__ vfb)
{
  // union: staging Xs(128x64)+Ws(64x64)=12288 ush | Tr q/k 8192 | Trv 64x132=8448
  __shared__ __align__(16) ushort_t smem[128 * 64 + 64 * 64];
  ushort_t* Xs = smem;
  ushort_t* Ws = smem + 128 * 64;
  const int tid  = threadIdx.x;
  const int wave = tid >> 6;
  const int lane = tid & 63;
  const int l15  = lane & 15, quad = lane >> 4;
  const int n0 = blockIdx.x * 64;
  const int m0 = blockIdx.y * 128;
  const int z  = blockIdx.z;
  const ushort_t* Wt = (z == 0) ? Wqb : (z == 1) ? Wkb : Wvb;
  const int h = n0 >> 6;

  f32x4 acc[2][4];
  #pragma unroll
  for (int i = 0; i < 2; ++i)
    #pragma unroll
    for (int j = 0; j < 4; ++j) acc[i][j] = (f32x4){0.f, 0.f, 0.f, 0.f};

  const int srX = tid >> 1, scX = (tid & 1) * 32;
  const int srW = tid >> 2, scW = (tid & 3) * 16;

  for (int k0 = 0; k0 < E; k0 += 64) {
    uint4 x0 = *(const uint4*)(Xb + (size_t)(m0 + srX) * E + k0 + scX);
    uint4 x1 = *(const uint4*)(Xb + (size_t)(m0 + srX) * E + k0 + scX + 8);
    uint4 x2 = *(const uint4*)(Xb + (size_t)(m0 + srX) * E + k0 + scX + 16);
    uint4 x3 = *(const uint4*)(Xb + (size_t)(m0 + srX) * E + k0 + scX + 24);
    uint4 w0 = *(const uint4*)(Wt + (size_t)(n0 + srW) * E + k0 + scW);
    uint4 w1 = *(const uint4*)(Wt + (size_t)(n0 + srW) * E + k0 + scW + 8);
    *(uint4*)&Xs[swz(srX, scX)]      = x0;
    *(uint4*)&Xs[swz(srX, scX + 8)]  = x1;
    *(uint4*)&Xs[swz(srX, scX + 16)] = x2;
    *(uint4*)&Xs[swz(srX, scX + 24)] = x3;
    *(uint4*)&Ws[swz(srW, scW)]      = w0;
    *(uint4*)&Ws[swz(srW, scW + 8)]  = w1;
    __syncthreads();
    short8 a[2][2];
    #pragma unroll
    for (int mt = 0; mt < 2; ++mt)
      #pragma unroll
      for (int kh = 0; kh < 2; ++kh)
        a[mt][kh] = *(const short8*)&Xs[swz(wave * 32 + mt * 16 + l15, kh * 32 + quad * 8)];
    #pragma unroll
    for (int nt = 0; nt < 4; ++nt) {
      #pragma unroll
      for (int kh = 0; kh < 2; ++kh) {
        short8 bb = *(const short8*)&Ws[swz(nt * 16 + l15, kh * 32 + quad * 8)];
        #pragma unroll
        for (int mt = 0; mt < 2; ++mt)
          acc[mt][nt] = __builtin_amdgcn_mfma_f32_16x16x32_bf16(a[mt][kh], bb, acc[mt][nt], 0, 0, 0);
      }
    }
    __syncthreads();
  }

  const int b  = m0 >> 11;
  const int t0 = m0 & (T - 1);
  const int bh = b * H + h;
  const float qscale = (z == 0) ? 0.125f : 1.0f;

  if (z < 2) {
    #pragma unroll
    for (int mt = 0; mt < 2; ++mt) {
      #pragma unroll
      for (int r = 0; r < 4; ++r) {
        int mloc = wave * 32 + mt * 16 + quad * 4 + r;
        int t = (m0 + mloc) & (T - 1);
        float s0 = acc[mt][0][r] * qscale;
        float s1 = acc[mt][1][r] * qscale;
        float c0v = ct[t * 32 + l15],      sn0 = st[t * 32 + l15];
        float c1v = ct[t * 32 + 16 + l15], sn1 = st[t * 32 + 16 + l15];
        smem[swz(mloc, l15)]      = f2bf(s0 * c0v - s1 * sn0);
        smem[swz(mloc, 16 + l15)] = f2bf(s1 * c1v + s0 * sn1);
        smem[swz(mloc, 32 + l15)] = f2bf(acc[mt][2][r] * qscale);
        smem[swz(mloc, 48 + l15)] = f2bf(acc[mt][3][r] * qscale);
      }
    }
    __syncthreads();
    if (z == 0) {
      // Qf pieces: p = [qtl:8][kh:2][lane:64]
      #pragma unroll
      for (int i = 0; i < 4; ++i) {
        int p = tid + 256 * i;
        int qtl = p >> 7, kh = (p >> 6) & 1, ln = p & 63;
        int tl = qtl * 16 + (ln & 15);
        int d  = kh * 32 + (ln >> 4) * 8;
        uint4 v = *(const uint4*)&smem[swz(tl, d)];
        size_t off = ((size_t)((bh * 128 + (t0 >> 4) + qtl) * 2 + kh)) * 512 + ln * 8;
        *(uint4*)(qfb + off) = v;
      }
    } else {
      // Kf pieces: p = [ktl:2][mt:4][kh:2][lane:64]
      #pragma unroll
      for (int i = 0; i < 4; ++i) {
        int p = tid + 256 * i;
        int ktl = p >> 9, mt = (p >> 7) & 3, kh = (p >> 6) & 1, ln = p & 63;
        int tl = ktl * 64 + mt * 16 + (ln & 15);
        int d  = kh * 32 + (ln >> 4) * 8;
        uint4 v = *(const uint4*)&smem[swz(tl, d)];
        size_t off = ((size_t)(((bh * 32 + (t0 >> 6) + ktl) * 4 + mt) * 2 + kh)) * 512 + ln * 8;
        *(uint4*)(kfb + off) = v;
      }
    }
  } else {
    #pragma unroll
    for (int mt = 0; mt < 2; ++mt) {
      #pragma unroll
      for (int r = 0; r < 4; ++r) {
        int mloc = wave * 32 + mt * 16 + quad * 4 + r;
        int t = (m0 + mloc) & (T - 1);
        float s0 = acc[mt][0][r], s1 = acc[mt][1][r];
        float c0v = ct[t * 32 + l15],      sn0 = st[t * 32 + l15];
        float c1v = ct[t * 32 + 16 + l15], sn1 = st[t * 32 + 16 + l15];
        smem[(l15)      * 132 + mloc] = f2bf(s0 * c0v - s1 * sn0);
        smem[(16 + l15) * 132 + mloc] = f2bf(s1 * c1v + s0 * sn1);
        smem[(32 + l15) * 132 + mloc] = f2bf(acc[mt][2][r]);
        smem[(48 + l15) * 132 + mloc] = f2bf(acc[mt][3][r]);
      }
    }
    __syncthreads();
    // Vf pieces: p = [ktl:2][nt:4][kh:2][lane:64]
    #pragma unroll
    for (int i = 0; i < 4; ++i) {
      int p = tid + 256 * i;
      int ktl = p >> 9, nt = (p >> 7) & 3, kh = (p >> 6) & 1, ln = p & 63;
      int d  = nt * 16 + (ln & 15);
      int tl = ktl * 64 + kh * 32 + (ln >> 4) * 8;
      uint4 v = *(const uint4*)&smem[d * 132 + tl];
      size_t off = ((size_t)(((bh * 32 + (t0 >> 6) + ktl) * 4 + nt) * 2 + kh)) * 512 + ln * 8;
      *(uint4*)(vfb + off) = v;
    }
  }
}

// ---------------------------------------------------------------------------
// Flash attention, K-SPLIT: block = (16-row q-group, bh), grid 128x24 = 3072
// blocks. Wave w handles k-tiles {w, w+4, ..., w+28} (8 tiles). Static-max
// softmax means partials combine by pure addition: one LDS reduction at end.
// No barriers in the K-loop; fragment-order global loads; wave-private P LDS.
// ---------------------------------------------------------------------------
__global__ __launch_bounds__(256, 5) void attn_kernel(
    const ushort_t* __restrict__ qfb, const ushort_t* __restrict__ kfb,
    const ushort_t* __restrict__ vfb, ushort_t* __restrict__ cbuf)
{
  __shared__ __align__(16) ushort_t Ps[4][16 * 64];   // wave-private P transpose
  __shared__ __align__(16) float Osh[4][16][68];      // per-wave O partials
  __shared__ float Lsh[4][16];                        // per-wave lsum partials
  const int tid  = threadIdx.x;
  const int wave = tid >> 6;
  const int lane = tid & 63;
  const int l15  = lane & 15, quad = lane >> 4;
  const int qg = blockIdx.x;          // 16-row q-group
  const int bh = blockIdx.y;
  const ushort_t* Qf = qfb + (size_t)bh * (T * HD);
  const ushort_t* Kf = kfb + (size_t)bh * (T * HD);
  const ushort_t* Vf = vfb + (size_t)bh * (T * HD);
  ushort_t* Pw = &Ps[wave][0];

  short8 qa[2];
  #pragma unroll
  for (int kh = 0; kh < 2; ++kh)
    qa[kh] = *(const short8*)(Qf + ((size_t)(qg * 2 + kh)) * 512 + lane * 8);

  f32x4 o[4];
  #pragma unroll
  for (int nt = 0; nt < 4; ++nt) o[nt] = (f32x4){0.f, 0.f, 0.f, 0.f};
  float lsum = 0.f;

  for (int kt = wave; kt < T / 64; kt += 4) {
    short8 ka[4][2], va[4][2];
    #pragma unroll
    for (int mt = 0; mt < 4; ++mt)
      #pragma unroll
      for (int kh = 0; kh < 2; ++kh) {
        ka[mt][kh] = *(const short8*)(Kf + ((size_t)((kt * 4 + mt) * 2 + kh)) * 512 + lane * 8);
        va[mt][kh] = *(const short8*)(Vf + ((size_t)((kt * 4 + mt) * 2 + kh)) * 512 + lane * 8);
      }

    // S^T: C row = kc (quad*4+r), col = q (l15)
    f32x4 ss[4];
    #pragma unroll
    for (int mt = 0; mt < 4; ++mt) ss[mt] = (f32x4){0.f, 0.f, 0.f, 0.f};
    #pragma unroll
    for (int mt = 0; mt < 4; ++mt) {
      ss[mt] = __builtin_amdgcn_mfma_f32_16x16x32_bf16(ka[mt][0], qa[0], ss[mt], 0, 0, 0);
      ss[mt] = __builtin_amdgcn_mfma_f32_16x16x32_bf16(ka[mt][1], qa[1], ss[mt], 0, 0, 0);
    }

    // exp + per-lane denominator + packed bf16 P write (wave-private LDS)
    #pragma unroll
    for (int mt = 0; mt < 4; ++mt) {
      float p0 = __expf(ss[mt][0]);
      float p1 = __expf(ss[mt][1]);
      float p2 = __expf(ss[mt][2]);
      float p3 = __expf(ss[mt][3]);
      lsum += (p0 + p1) + (p2 + p3);
      uint2 w2;
      w2.x = pack_bf2(p0, p1);
      w2.y = pack_bf2(p2, p3);
      *(uint2*)&Pw[swz(l15, mt * 16 + quad * 4)] = w2;
    }

    // PV: A = P (row = q = l15), B = V fragment
    short8 pa0 = *(const short8*)&Pw[swz(l15, quad * 8)];
    short8 pa1 = *(const short8*)&Pw[swz(l15, 32 + quad * 8)];
    #pragma unroll
    for (int nt = 0; nt < 4; ++nt) {
      o[nt] = __builtin_amdgcn_mfma_f32_16x16x32_bf16(pa0, va[nt][0], o[nt], 0, 0, 0);
      o[nt] = __builtin_amdgcn_mfma_f32_16x16x32_bf16(pa1, va[nt][1], o[nt], 0, 0, 0);
    }
  }

  // intra-wave: all lanes end with full k-partial sum for q = l15
  lsum += __shfl_xor(lsum, 16);
  lsum += __shfl_xor(lsum, 32);
  if (lane < 16) Lsh[wave][l15] = lsum;

  // per-wave O partial to LDS (C-layout scatter; 68-pad keeps <=2-way banks)
  #pragma unroll
  for (int nt = 0; nt < 4; ++nt)
    #pragma unroll
    for (int r = 0; r < 4; ++r)
      Osh[wave][quad * 4 + r][nt * 16 + l15] = o[nt][r];
  __syncthreads();

  // cross-wave reduce + normalize + store. thread: row=tid>>4, 4 cols.
  const int row = tid >> 4;
  const int c4  = (tid & 15) * 4;
  float4 s = *(const float4*)&Osh[0][row][c4];
  #pragma unroll
  for (int w = 1; w < 4; ++w) {
    float4 t = *(const float4*)&Osh[w][row][c4];
    s.x += t.x; s.y += t.y; s.z += t.z; s.w += t.w;
  }
  float inv = 1.0f / (Lsh[0][row] + Lsh[1][row] + Lsh[2][row] + Lsh[3][row]);
  const int b = bh / H, h = bh % H;
  int t = qg * 16 + row;
  size_t base = ((size_t)b * T + t) * E + h * HD + c4;
  uint2 w2;
  w2.x = pack_bf2(s.x * inv, s.y * inv);
  w2.y = pack_bf2(s.z * inv, s.w * inv);
  *(uint2*)(cbuf + base) = w2;
}

// ---------------------------------------------------------------------------
// Output projection, 128x64 bf16 MFMA tile, K-step 64 (12 iters), fp32 + bias.
// ---------------------------------------------------------------------------
__global__ __launch_bounds__(256) void out_gemm(
    const ushort_t* __restrict__ Xc, const ushort_t* __restrict__ Wob,
    const float* __restrict__ bo, float* __restrict__ out)
{
  __shared__ __align__(16) ushort_t Xs[128 * 64];
  __shared__ __align__(16) ushort_t Ws[64 * 64];
  const int tid  = threadIdx.x;
  const int wave = tid >> 6;
  const int lane = tid & 63;
  const int l15  = lane & 15, quad = lane >> 4;
  const int n0 = blockIdx.x * 64;
  const int m0 = blockIdx.y * 128;

  f32x4 acc[2][4];
  #pragma unroll
  for (int i = 0; i < 2; ++i)
    #pragma unroll
    for (int j = 0; j < 4; ++j) acc[i][j] = (f32x4){0.f, 0.f, 0.f, 0.f};

  const int srX = tid >> 1, scX = (tid & 1) * 32;
  const int srW = tid >> 2, scW = (tid & 3) * 16;

  for (int k0 = 0; k0 < E; k0 += 64) {
    uint4 x0 = *(const uint4*)(Xc + (size_t)(m0 + srX) * E + k0 + scX);
    uint4 x1 = *(const uint4*)(Xc + (size_t)(m0 + srX) * E + k0 + scX + 8);
    uint4 x2 = *(const uint4*)(Xc + (size_t)(m0 + srX) * E + k0 + scX + 16);
    uint4 x3 = *(const uint4*)(Xc + (size_t)(m0 + srX) * E + k0 + scX + 24);
    uint4 w0 = *(const uint4*)(Wob + (size_t)(n0 + srW) * E + k0 + scW);
    uint4 w1 = *(const uint4*)(Wob + (size_t)(n0 + srW) * E + k0 + scW + 8);
    *(uint4*)&Xs[swz(srX, scX)]      = x0;
    *(uint4*)&Xs[swz(srX, scX + 8)]  = x1;
    *(uint4*)&Xs[swz(srX, scX + 16)] = x2;
    *(uint4*)&Xs[swz(srX, scX + 24)] = x3;
    *(uint4*)&Ws[swz(srW, scW)]      = w0;
    *(uint4*)&Ws[swz(srW, scW + 8)]  = w1;
    __syncthreads();
    short8 a[2][2];
    #pragma unroll
    for (int mt = 0; mt < 2; ++mt)
      #pragma unroll
      for (int kh = 0; kh < 2; ++kh)
        a[mt][kh] = *(const short8*)&Xs[swz(wave * 32 + mt * 16 + l15, kh * 32 + quad * 8)];
    #pragma unroll
    for (int nt = 0; nt < 4; ++nt) {
      #pragma unroll
      for (int kh = 0; kh < 2; ++kh) {
        short8 bb = *(const short8*)&Ws[swz(nt * 16 + l15, kh * 32 + quad * 8)];
        #pragma unroll
        for (int mt = 0; mt < 2; ++mt)
          acc[mt][nt] = __builtin_amdgcn_mfma_f32_16x16x32_bf16(a[mt][kh], bb, acc[mt][nt], 0, 0, 0);
      }
    }
    __syncthreads();
  }

  float bias[4];
  #pragma unroll
  for (int nt = 0; nt < 4; ++nt) bias[nt] = bo[n0 + nt * 16 + l15];
  #pragma unroll
  for (int mt = 0; mt < 2; ++mt) {
    #pragma unroll
    for (int r = 0; r < 4; ++r) {
      int m = m0 + wave * 32 + mt * 16 + quad * 4 + r;
      float* op = out + (size_t)m * E + n0;
      op[l15]      = acc[mt][0][r] + bias[0];
      op[16 + l15] = acc[mt][1][r] + bias[1];
      op[32 + l15] = acc[mt][2][r] + bias[2];
      op[48 + l15] = acc[mt][3][r] + bias[3];
    }
  }
}

// ---------------------------------------------------------------------------
extern "C" void kernel_launch(void* const* d_in, const int* in_sizes, int n_in,
                              void* d_out, int out_size, void* d_ws, size_t ws_size,
                              hipStream_t stream) {
  (void)in_sizes; (void)n_in; (void)out_size; (void)ws_size;
  const float* X    = (const float*)d_in[0];
  const float* rope = (const float*)d_in[1];
  const float* Wq   = (const float*)d_in[2];
  const float* Wk   = (const float*)d_in[3];
  const float* Wv   = (const float*)d_in[4];
  const float* Wo   = (const float*)d_in[5];
  const float* bo   = (const float*)d_in[6];
  float* out = (float*)d_out;

  const size_t NX = (size_t)B * T * E;
  const size_t NW = (size_t)E * E;
  const size_t NR = (size_t)T * 32;
  ushort_t* Xb  = (ushort_t*)d_ws;
  ushort_t* Wqb = Xb  + NX;
  ushort_t* Wkb = Wqb + NW;
  ushort_t* Wvb = Wkb + NW;
  ushort_t* Wob = Wvb + NW;
  ushort_t* qfb = Wob + NW;
  ushort_t* kfb = qfb + NX;
  ushort_t* vfb = kfb + NX;
  ushort_t* cb  = vfb + NX;
  float* ct = (float*)(cb + NX);
  float* st = ct + NR;

  const int total4 = (int)((NX + 4 * NW + NR) / 4);
  cvt_all<<<total4 / 256, 256, 0, stream>>>(X, Wq, Wk, Wv, Wo, rope,
                                            Xb, Wqb, Wkb, Wvb, Wob, ct, st);

  qkv_gemm<<<dim3(E / 64, (B * T) / 128, 3), 256, 0, stream>>>(
      Xb, Wqb, Wkb, Wvb, ct, st, qfb, kfb, vfb);
  attn_kernel<<<dim3(T / 16, B * H), 256, 0, stream>>>(qfb, kfb, vfb, cb);
  out_gemm<<<dim3(E / 64, (B * T) / 128), 256, 0, stream>>>(cb, Wob, bo, out);
}

// Round 8
// 182.260 us; speedup vs baseline: 1.0179x; 1.0179x over previous
//
#include <hip/hip_runtime.h>
#include <hip/hip_bf16.h>

typedef unsigned short ushort_t;
typedef __attribute__((ext_vector_type(8))) short short8;
typedef __attribute__((ext_vector_type(4))) float f32x4;

constexpr int B  = 2;
constexpr int T  = 2048;
constexpr int E  = 768;
constexpr int H  = 12;
constexpr int HD = 64;

__device__ __forceinline__ ushort_t f2bf(float x) {
  unsigned int u = __float_as_uint(x);
  u += 0x7fffu + ((u >> 16) & 1u);
  return (ushort_t)(u >> 16);
}

__device__ __forceinline__ unsigned int pack_bf2(float a, float b) {
  __hip_bfloat162 h = __float22bfloat162_rn(float2{a, b});
  return *(unsigned int*)&h;
}

// XOR-swizzled LDS index, 64-ushort rows: 16B chunks, chunk ^= row&7.
__device__ __forceinline__ int swz(int row, int col) {
  return row * 64 + ((((col >> 3) ^ (row & 7)) << 3) | (col & 7));
}

// ---------------------------------------------------------------------------
// Fused: fp32->bf16 convert for X + 4 weights, AND fp32 cos/sin rope tables.
// ---------------------------------------------------------------------------
__global__ __launch_bounds__(256) void cvt_all(
    const float* __restrict__ X,  const float* __restrict__ Wq,
    const float* __restrict__ Wk, const float* __restrict__ Wv,
    const float* __restrict__ Wo, const float* __restrict__ rope,
    ushort_t* __restrict__ Xb,  ushort_t* __restrict__ Wqb,
    ushort_t* __restrict__ Wkb, ushort_t* __restrict__ Wvb,
    ushort_t* __restrict__ Wob, float* __restrict__ ct, float* __restrict__ st)
{
  constexpr int NX4 = (B * T * E) / 4;
  constexpr int NW4 = (E * E) / 4;
  constexpr int NC4 = NX4 + 4 * NW4;
  int i = blockIdx.x * 256 + threadIdx.x;
  if (i < NC4) {
    const float* s; ushort_t* d; int j;
    if (i < NX4) { s = X; d = Xb; j = i; }
    else {
      int t = i - NX4;
      int w = t / NW4; j = t - w * NW4;
      s = (w == 0) ? Wq : (w == 1) ? Wk : (w == 2) ? Wv : Wo;
      d = (w == 0) ? Wqb : (w == 1) ? Wkb : (w == 2) ? Wvb : Wob;
    }
    float4 v = ((const float4*)s)[j];
    ushort4 o;
    o.x = f2bf(v.x); o.y = f2bf(v.y); o.z = f2bf(v.z); o.w = f2bf(v.w);
    ((ushort4*)d)[j] = o;
  } else {
    int j = (i - NC4) * 4;
    float4 f = *(const float4*)(rope + j);
    float c, s;
    sincosf(f.x, &s, &c); ct[j+0] = c; st[j+0] = s;
    sincosf(f.y, &s, &c); ct[j+1] = c; st[j+1] = s;
    sincosf(f.z, &s, &c); ct[j+2] = c; st[j+2] = s;
    sincosf(f.w, &s, &c); ct[j+3] = c; st[j+3] = s;
  }
}

// ---------------------------------------------------------------------------
// QKV projection, bf16 MFMA. Tile 128(M) x 128(N = two heads), K-step 64,
// 2x2 waves (64x64 each), 32 MFMAs/wave per barrier pair. Rotary via tables.
// Each wave's 64-col half is exactly one head, so rotary stays per-wave.
// Epilogue via LDS transpose (stride 132 -> conflict-light), coalesced uint4:
//   q/k -> (bh,t,d) row-major;  v -> (bh,d,t) transposed.
// ---------------------------------------------------------------------------
__global__ __launch_bounds__(256) void qkv_gemm(
    const ushort_t* __restrict__ Xb,
    const ushort_t* __restrict__ Wqb, const ushort_t* __restrict__ Wkb,
    const ushort_t* __restrict__ Wvb,
    const float* __restrict__ ct, const float* __restrict__ st,
    ushort_t* __restrict__ qb, ushort_t* __restrict__ kb, ushort_t* __restrict__ vtb)
{
  // union: staging Xs(128x64)+Ws(128x64)=16384 ush | Tr 128x132 (or 2x64x132) = 16896 ush
  __shared__ __align__(16) ushort_t smem[128 * 132];
  ushort_t* Xs = smem;
  ushort_t* Ws = smem + 128 * 64;
  const int tid  = threadIdx.x;
  const int wave = tid >> 6;
  const int lane = tid & 63;
  const int l15  = lane & 15, quad = lane >> 4;
  const int ww = wave >> 1, wn = wave & 1;     // 2x2 wave grid
  const int n0 = blockIdx.x * 128;
  const int m0 = blockIdx.y * 128;
  const int z  = blockIdx.z;
  const ushort_t* Wt = (z == 0) ? Wqb : (z == 1) ? Wkb : Wvb;
  const int h0 = n0 >> 6;                      // first of the two heads

  f32x4 acc[4][4];
  #pragma unroll
  for (int i = 0; i < 4; ++i)
    #pragma unroll
    for (int j = 0; j < 4; ++j) acc[i][j] = (f32x4){0.f, 0.f, 0.f, 0.f};

  const int srow = tid >> 1, sc = (tid & 1) * 32;

  for (int k0 = 0; k0 < E; k0 += 64) {
    uint4 x0 = *(const uint4*)(Xb + (size_t)(m0 + srow) * E + k0 + sc);
    uint4 x1 = *(const uint4*)(Xb + (size_t)(m0 + srow) * E + k0 + sc + 8);
    uint4 x2 = *(const uint4*)(Xb + (size_t)(m0 + srow) * E + k0 + sc + 16);
    uint4 x3 = *(const uint4*)(Xb + (size_t)(m0 + srow) * E + k0 + sc + 24);
    uint4 w0 = *(const uint4*)(Wt + (size_t)(n0 + srow) * E + k0 + sc);
    uint4 w1 = *(const uint4*)(Wt + (size_t)(n0 + srow) * E + k0 + sc + 8);
    uint4 w2 = *(const uint4*)(Wt + (size_t)(n0 + srow) * E + k0 + sc + 16);
    uint4 w3 = *(const uint4*)(Wt + (size_t)(n0 + srow) * E + k0 + sc + 24);
    *(uint4*)&Xs[swz(srow, sc)]      = x0;
    *(uint4*)&Xs[swz(srow, sc + 8)]  = x1;
    *(uint4*)&Xs[swz(srow, sc + 16)] = x2;
    *(uint4*)&Xs[swz(srow, sc + 24)] = x3;
    *(uint4*)&Ws[swz(srow, sc)]      = w0;
    *(uint4*)&Ws[swz(srow, sc + 8)]  = w1;
    *(uint4*)&Ws[swz(srow, sc + 16)] = w2;
    *(uint4*)&Ws[swz(srow, sc + 24)] = w3;
    __syncthreads();
    short8 a[4][2];
    #pragma unroll
    for (int mt = 0; mt < 4; ++mt)
      #pragma unroll
      for (int kh = 0; kh < 2; ++kh)
        a[mt][kh] = *(const short8*)&Xs[swz(ww * 64 + mt * 16 + l15, kh * 32 + quad * 8)];
    #pragma unroll
    for (int nt = 0; nt < 4; ++nt) {
      #pragma unroll
      for (int kh = 0; kh < 2; ++kh) {
        short8 bb = *(const short8*)&Ws[swz(wn * 64 + nt * 16 + l15, kh * 32 + quad * 8)];
        #pragma unroll
        for (int mt = 0; mt < 4; ++mt)
          acc[mt][nt] = __builtin_amdgcn_mfma_f32_16x16x32_bf16(a[mt][kh], bb, acc[mt][nt], 0, 0, 0);
      }
    }
    __syncthreads();
  }

  const int b  = m0 >> 11;
  const int t0 = m0 & (T - 1);
  const float qscale = (z == 0) ? 0.125f : 1.0f;

  if (z < 2) {
    // rotate in regs, write Tq[t_local:128][col:128] stride 132, coalesced store
    #pragma unroll
    for (int mt = 0; mt < 4; ++mt) {
      #pragma unroll
      for (int r = 0; r < 4; ++r) {
        int tl = ww * 64 + mt * 16 + quad * 4 + r;
        int t  = t0 + tl;
        float s0 = acc[mt][0][r] * qscale;
        float s1 = acc[mt][1][r] * qscale;
        float c0v = ct[t * 32 + l15],      sn0 = st[t * 32 + l15];
        float c1v = ct[t * 32 + 16 + l15], sn1 = st[t * 32 + 16 + l15];
        ushort_t* row = smem + tl * 132 + wn * 64;
        row[l15]      = f2bf(s0 * c0v - s1 * sn0);
        row[16 + l15] = f2bf(s1 * c1v + s0 * sn1);
        row[32 + l15] = f2bf(acc[mt][2][r] * qscale);
        row[48 + l15] = f2bf(acc[mt][3][r] * qscale);
      }
    }
    __syncthreads();
    ushort_t* dst = (z == 0) ? qb : kb;
    int row = tid >> 1, half = tid & 1;
    int t = t0 + row, h = h0 + half;
    size_t base = ((size_t)(b * H + h) * T + t) * HD;
    #pragma unroll
    for (int c = 0; c < 64; c += 8)
      *(uint4*)(dst + base + c) = *(const uint4*)&smem[row * 132 + half * 64 + c];
  } else {
    // V: rotate, per-head transpose Tv[head:2][d:64][t:128] stride 132
    ushort_t* Tv = smem + wn * (64 * 132);
    #pragma unroll
    for (int mt = 0; mt < 4; ++mt) {
      #pragma unroll
      for (int r = 0; r < 4; ++r) {
        int tl = ww * 64 + mt * 16 + quad * 4 + r;
        int t  = t0 + tl;
        float s0 = acc[mt][0][r], s1 = acc[mt][1][r];
        float c0v = ct[t * 32 + l15],      sn0 = st[t * 32 + l15];
        float c1v = ct[t * 32 + 16 + l15], sn1 = st[t * 32 + 16 + l15];
        Tv[(l15)      * 132 + tl] = f2bf(s0 * c0v - s1 * sn0);
        Tv[(16 + l15) * 132 + tl] = f2bf(s1 * c1v + s0 * sn1);
        Tv[(32 + l15) * 132 + tl] = f2bf(acc[mt][2][r]);
        Tv[(48 + l15) * 132 + tl] = f2bf(acc[mt][3][r]);
      }
    }
    __syncthreads();
    int hh = tid >> 7, d = (tid >> 1) & 63, c0 = (tid & 1) * 64;
    const ushort_t* Trh = smem + hh * (64 * 132);
    size_t obase = ((size_t)(b * H + h0 + hh) * HD + d) * (size_t)T + t0 + c0;
    #pragma unroll
    for (int c = 0; c < 64; c += 8)
      *(uint4*)(vtb + obase + c) = *(const uint4*)&Trh[d * 132 + c0 + c];
  }
}

// ---------------------------------------------------------------------------
// Flash attention (R5-proven). Block = 64 q-rows x bh (768 blocks); 4 waves,
// wave owns 16 q. Double-buffered K/V (ONE barrier/tile), XOR-swizzled LDS,
// Q fragments from global, static max, per-lane denominator.
// ---------------------------------------------------------------------------
__global__ __launch_bounds__(256, 4) void attn_kernel(
    const ushort_t* __restrict__ qbuf, const ushort_t* __restrict__ kbuf,
    const ushort_t* __restrict__ vtbuf, ushort_t* __restrict__ cbuf)
{
  __shared__ __align__(16) ushort_t Ks[2][64 * 64];
  __shared__ __align__(16) ushort_t Vt[2][64 * 64];
  __shared__ __align__(16) ushort_t Ps[64 * 64];
  const int tid  = threadIdx.x;
  const int wave = tid >> 6;
  const int lane = tid & 63;
  const int l15  = lane & 15, quad = lane >> 4;
  const int q0 = blockIdx.x * 64;
  const int bh = blockIdx.y;
  const ushort_t* Qg = qbuf  + (size_t)bh * T * HD;
  const ushort_t* Kg = kbuf  + (size_t)bh * T * HD;
  const ushort_t* Vg = vtbuf + (size_t)bh * HD * T;

  short8 qa[2];
  #pragma unroll
  for (int hf = 0; hf < 2; ++hf)
    qa[hf] = *(const short8*)(Qg + (size_t)(q0 + wave * 16 + l15) * HD + hf * 32 + quad * 8);

  const int srow = tid >> 2, cb0 = (tid & 3) * 16;
  {
    uint4 ka = *(const uint4*)(Kg + (size_t)srow * HD + cb0);
    uint4 kc = *(const uint4*)(Kg + (size_t)srow * HD + cb0 + 8);
    uint4 va = *(const uint4*)(Vg + (size_t)srow * T + cb0);
    uint4 vc = *(const uint4*)(Vg + (size_t)srow * T + cb0 + 8);
    *(uint4*)&Ks[0][swz(srow, cb0)]     = ka;
    *(uint4*)&Ks[0][swz(srow, cb0 + 8)] = kc;
    *(uint4*)&Vt[0][swz(srow, cb0)]     = va;
    *(uint4*)&Vt[0][swz(srow, cb0 + 8)] = vc;
  }
  __syncthreads();

  f32x4 o[4];
  #pragma unroll
  for (int nt = 0; nt < 4; ++nt) o[nt] = (f32x4){0.f, 0.f, 0.f, 0.f};
  float lsum = 0.f;

  for (int kt = 0; kt < T; kt += 64) {
    const int cur = (kt >> 6) & 1;
    const bool more = (kt + 64) < T;
    uint4 nk0, nk1, nv0, nv1;
    if (more) {
      nk0 = *(const uint4*)(Kg + (size_t)(kt + 64 + srow) * HD + cb0);
      nk1 = *(const uint4*)(Kg + (size_t)(kt + 64 + srow) * HD + cb0 + 8);
      nv0 = *(const uint4*)(Vg + (size_t)srow * T + kt + 64 + cb0);
      nv1 = *(const uint4*)(Vg + (size_t)srow * T + kt + 64 + cb0 + 8);
    }

    // S^T: C row = kc (quad*4+r within mt tile), col = q (l15)
    f32x4 ss[4];
    #pragma unroll
    for (int mt = 0; mt < 4; ++mt) ss[mt] = (f32x4){0.f, 0.f, 0.f, 0.f};
    #pragma unroll
    for (int mt = 0; mt < 4; ++mt) {
      int row = mt * 16 + l15;
      short8 ka0 = *(const short8*)&Ks[cur][swz(row, quad * 8)];
      short8 ka1 = *(const short8*)&Ks[cur][swz(row, 32 + quad * 8)];
      ss[mt] = __builtin_amdgcn_mfma_f32_16x16x32_bf16(ka0, qa[0], ss[mt], 0, 0, 0);
      ss[mt] = __builtin_amdgcn_mfma_f32_16x16x32_bf16(ka1, qa[1], ss[mt], 0, 0, 0);
    }

    // exp + per-lane denominator + packed bf16 P write (no cross-lane ops)
    const int rp = wave * 16 + l15;
    #pragma unroll
    for (int mt = 0; mt < 4; ++mt) {
      float p0 = __expf(ss[mt][0]);
      float p1 = __expf(ss[mt][1]);
      float p2 = __expf(ss[mt][2]);
      float p3 = __expf(ss[mt][3]);
      lsum += (p0 + p1) + (p2 + p3);
      uint2 w2;
      w2.x = pack_bf2(p0, p1);
      w2.y = pack_bf2(p2, p3);
      *(uint2*)&Ps[swz(rp, mt * 16 + quad * 4)] = w2;
    }

    // PV: A = P (wave-private rows), B = V^T
    short8 pa0 = *(const short8*)&Ps[swz(rp, quad * 8)];
    short8 pa1 = *(const short8*)&Ps[swz(rp, 32 + quad * 8)];
    #pragma unroll
    for (int nt = 0; nt < 4; ++nt) {
      int vr = nt * 16 + l15;
      short8 vb0 = *(const short8*)&Vt[cur][swz(vr, quad * 8)];
      short8 vb1 = *(const short8*)&Vt[cur][swz(vr, 32 + quad * 8)];
      o[nt] = __builtin_amdgcn_mfma_f32_16x16x32_bf16(pa0, vb0, o[nt], 0, 0, 0);
      o[nt] = __builtin_amdgcn_mfma_f32_16x16x32_bf16(pa1, vb1, o[nt], 0, 0, 0);
    }

    if (more) {
      const int nxt = cur ^ 1;
      *(uint4*)&Ks[nxt][swz(srow, cb0)]     = nk0;
      *(uint4*)&Ks[nxt][swz(srow, cb0 + 8)] = nk1;
      *(uint4*)&Vt[nxt][swz(srow, cb0)]     = nv0;
      *(uint4*)&Vt[nxt][swz(srow, cb0 + 8)] = nv1;
    }
    __syncthreads();
  }

  lsum += __shfl_xor(lsum, 16);
  lsum += __shfl_xor(lsum, 32);

  const int b = bh / H, h = bh % H;
  #pragma unroll
  for (int r = 0; r < 4; ++r) {
    float lr = __shfl(lsum, quad * 4 + r);
    float inv = 1.0f / lr;
    int t = q0 + wave * 16 + quad * 4 + r;
    size_t base = ((size_t)b * T + t) * E + h * HD;
    cbuf[base + l15]      = f2bf(o[0][r] * inv);
    cbuf[base + 16 + l15] = f2bf(o[1][r] * inv);
    cbuf[base + 32 + l15] = f2bf(o[2][r] * inv);
    cbuf[base + 48 + l15] = f2bf(o[3][r] * inv);
  }
}

// ---------------------------------------------------------------------------
// Output projection, 128x64 bf16 MFMA tile, K-step 64 (12 iters), fp32 + bias.
// ---------------------------------------------------------------------------
__global__ __launch_bounds__(256) void out_gemm(
    const ushort_t* __restrict__ Xc, const ushort_t* __restrict__ Wob,
    const float* __restrict__ bo, float* __restrict__ out)
{
  __shared__ __align__(16) ushort_t Xs[128 * 64];
  __shared__ __align__(16) ushort_t Ws[64 * 64];
  const int tid  = threadIdx.x;
  const int wave = tid >> 6;
  const int lane = tid & 63;
  const int l15  = lane & 15, quad = lane >> 4;
  const int n0 = blockIdx.x * 64;
  const int m0 = blockIdx.y * 128;

  f32x4 acc[2][4];
  #pragma unroll
  for (int i = 0; i < 2; ++i)
    #pragma unroll
    for (int j = 0; j < 4; ++j) acc[i][j] = (f32x4){0.f, 0.f, 0.f, 0.f};

  const int srX = tid >> 1, scX = (tid & 1) * 32;
  const int srW = tid >> 2, scW = (tid & 3) * 16;

  for (int k0 = 0; k0 < E; k0 += 64) {
    uint4 x0 = *(const uint4*)(Xc + (size_t)(m0 + srX) * E + k0 + scX);
    uint4 x1 = *(const uint4*)(Xc + (size_t)(m0 + srX) * E + k0 + scX + 8);
    uint4 x2 = *(const uint4*)(Xc + (size_t)(m0 + srX) * E + k0 + scX + 16);
    uint4 x3 = *(const uint4*)(Xc + (size_t)(m0 + srX) * E + k0 + scX + 24);
    uint4 w0 = *(const uint4*)(Wob + (size_t)(n0 + srW) * E + k0 + scW);
    uint4 w1 = *(const uint4*)(Wob + (size_t)(n0 + srW) * E + k0 + scW + 8);
    *(uint4*)&Xs[swz(srX, scX)]      = x0;
    *(uint4*)&Xs[swz(srX, scX + 8)]  = x1;
    *(uint4*)&Xs[swz(srX, scX + 16)] = x2;
    *(uint4*)&Xs[swz(srX, scX + 24)] = x3;
    *(uint4*)&Ws[swz(srW, scW)]      = w0;
    *(uint4*)&Ws[swz(srW, scW + 8)]  = w1;
    __syncthreads();
    short8 a[2][2];
    #pragma unroll
    for (int mt = 0; mt < 2; ++mt)
      #pragma unroll
      for (int kh = 0; kh < 2; ++kh)
        a[mt][kh] = *(const short8*)&Xs[swz(wave * 32 + mt * 16 + l15, kh * 32 + quad * 8)];
    #pragma unroll
    for (int nt = 0; nt < 4; ++nt) {
      #pragma unroll
      for (int kh = 0; kh < 2; ++kh) {
        short8 bb = *(const short8*)&Ws[swz(nt * 16 + l15, kh * 32 + quad * 8)];
        #pragma unroll
        for (int mt = 0; mt < 2; ++mt)
          acc[mt][nt] = __builtin_amdgcn_mfma_f32_16x16x32_bf16(a[mt][kh], bb, acc[mt][nt], 0, 0, 0);
      }
    }
    __syncthreads();
  }

  float bias[4];
  #pragma unroll
  for (int nt = 0; nt < 4; ++nt) bias[nt] = bo[n0 + nt * 16 + l15];
  #pragma unroll
  for (int mt = 0; mt < 2; ++mt) {
    #pragma unroll
    for (int r = 0; r < 4; ++r) {
      int m = m0 + wave * 32 + mt * 16 + quad * 4 + r;
      float* op = out + (size_t)m * E + n0;
      op[l15]      = acc[mt][0][r] + bias[0];
      op[16 + l15] = acc[mt][1][r] + bias[1];
      op[32 + l15] = acc[mt][2][r] + bias[2];
      op[48 + l15] = acc[mt][3][r] + bias[3];
    }
  }
}

// ---------------------------------------------------------------------------
extern "C" void kernel_launch(void* const* d_in, const int* in_sizes, int n_in,
                              void* d_out, int out_size, void* d_ws, size_t ws_size,
                              hipStream_t stream) {
  (void)in_sizes; (void)n_in; (void)out_size; (void)ws_size;
  const float* X    = (const float*)d_in[0];
  const float* rope = (const float*)d_in[1];
  const float* Wq   = (const float*)d_in[2];
  const float* Wk   = (const float*)d_in[3];
  const float* Wv   = (const float*)d_in[4];
  const float* Wo   = (const float*)d_in[5];
  const float* bo   = (const float*)d_in[6];
  float* out = (float*)d_out;

  const size_t NX = (size_t)B * T * E;
  const size_t NW = (size_t)E * E;
  const size_t NR = (size_t)T * 32;
  ushort_t* Xb  = (ushort_t*)d_ws;
  ushort_t* Wqb = Xb  + NX;
  ushort_t* Wkb = Wqb + NW;
  ushort_t* Wvb = Wkb + NW;
  ushort_t* Wob = Wvb + NW;
  ushort_t* qb  = Wob + NW;
  ushort_t* kb  = qb  + NX;
  ushort_t* vtb = kb  + NX;
  ushort_t* cb  = vtb + NX;
  float* ct = (float*)(cb + NX);
  float* st = ct + NR;

  const int total4 = (int)((NX + 4 * NW + NR) / 4);
  cvt_all<<<total4 / 256, 256, 0, stream>>>(X, Wq, Wk, Wv, Wo, rope,
                                            Xb, Wqb, Wkb, Wvb, Wob, ct, st);

  qkv_gemm<<<dim3(E / 128, (B * T) / 128, 3), 256, 0, stream>>>(
      Xb, Wqb, Wkb, Wvb, ct, st, qb, kb, vtb);
  attn_kernel<<<dim3(T / 64, B * H), 256, 0, stream>>>(qb, kb, vtb, cb);
  out_gemm<<<dim3(E / 64, (B * T) / 128), 256, 0, stream>>>(cb, Wob, bo, out);
}

// Round 9
// 166.154 us; speedup vs baseline: 1.1165x; 1.0969x over previous
//
#include <hip/hip_runtime.h>
#include <hip/hip_bf16.h>

typedef unsigned short ushort_t;
typedef __attribute__((ext_vector_type(8))) short short8;
typedef __attribute__((ext_vector_type(4))) float f32x4;

constexpr int B  = 2;
constexpr int T  = 2048;
constexpr int E  = 768;
constexpr int H  = 12;
constexpr int HD = 64;

__device__ __forceinline__ ushort_t f2bf(float x) {
  unsigned int u = __float_as_uint(x);
  u += 0x7fffu + ((u >> 16) & 1u);
  return (ushort_t)(u >> 16);
}

__device__ __forceinline__ unsigned int pack_bf2(float a, float b) {
  __hip_bfloat162 h = __float22bfloat162_rn(float2{a, b});
  return *(unsigned int*)&h;
}

// XOR-swizzled LDS index, 64-ushort rows: 16B chunks, chunk ^= row&7.
__device__ __forceinline__ int swz(int row, int col) {
  return row * 64 + ((((col >> 3) ^ (row & 7)) << 3) | (col & 7));
}

// ---------------------------------------------------------------------------
// Fused: fp32->bf16 convert for X + 4 weights, AND fp32 cos/sin rope tables.
// ---------------------------------------------------------------------------
__global__ __launch_bounds__(256) void cvt_all(
    const float* __restrict__ X,  const float* __restrict__ Wq,
    const float* __restrict__ Wk, const float* __restrict__ Wv,
    const float* __restrict__ Wo, const float* __restrict__ rope,
    ushort_t* __restrict__ Xb,  ushort_t* __restrict__ Wqb,
    ushort_t* __restrict__ Wkb, ushort_t* __restrict__ Wvb,
    ushort_t* __restrict__ Wob, float* __restrict__ ct, float* __restrict__ st)
{
  constexpr int NX4 = (B * T * E) / 4;
  constexpr int NW4 = (E * E) / 4;
  constexpr int NC4 = NX4 + 4 * NW4;
  int i = blockIdx.x * 256 + threadIdx.x;
  if (i < NC4) {
    const float* s; ushort_t* d; int j;
    if (i < NX4) { s = X; d = Xb; j = i; }
    else {
      int t = i - NX4;
      int w = t / NW4; j = t - w * NW4;
      s = (w == 0) ? Wq : (w == 1) ? Wk : (w == 2) ? Wv : Wo;
      d = (w == 0) ? Wqb : (w == 1) ? Wkb : (w == 2) ? Wvb : Wob;
    }
    float4 v = ((const float4*)s)[j];
    ushort4 o;
    o.x = f2bf(v.x); o.y = f2bf(v.y); o.z = f2bf(v.z); o.w = f2bf(v.w);
    ((ushort4*)d)[j] = o;
  } else {
    int j = (i - NC4) * 4;
    float4 f = *(const float4*)(rope + j);
    float c, s;
    sincosf(f.x, &s, &c); ct[j+0] = c; st[j+0] = s;
    sincosf(f.y, &s, &c); ct[j+1] = c; st[j+1] = s;
    sincosf(f.z, &s, &c); ct[j+2] = c; st[j+2] = s;
    sincosf(f.w, &s, &c); ct[j+3] = c; st[j+3] = s;
  }
}

// ---------------------------------------------------------------------------
// QKV projection (R7-proven). Tile 128(M)x64(N=one head), K-step 64. Rotary
// via tables. Epilogue writes MFMA FRAGMENT-ORDER global layouts:
//   Qf: per bh, per 16-q group: [kh:2][lane:64][8]  (B-frag, n=q)
//   Kf: per bh, per 64-k tile:  [mt:4][kh:2][lane:64][8]  (A-frag, m=kc)
//   Vf: per bh, per 64-k tile:  [nt:4][kh:2][lane:64][8]  (B-frag, n=d, k=kc;
//       kh indexes the kc half)
// ---------------------------------------------------------------------------
__global__ __launch_bounds__(256) void qkv_gemm(
    const ushort_t* __restrict__ Xb,
    const ushort_t* __restrict__ Wqb, const ushort_t* __restrict__ Wkb,
    const ushort_t* __restrict__ Wvb,
    const float* __restrict__ ct, const float* __restrict__ st,
    ushort_t* __restrict__ qfb, ushort_t* __restrict__ kfb, ushort_t* __restrict__ vfb)
{
  __shared__ __align__(16) ushort_t smem[128 * 64 + 64 * 64];
  ushort_t* Xs = smem;
  ushort_t* Ws = smem + 128 * 64;
  const int tid  = threadIdx.x;
  const int wave = tid >> 6;
  const int lane = tid & 63;
  const int l15  = lane & 15, quad = lane >> 4;
  const int n0 = blockIdx.x * 64;
  const int m0 = blockIdx.y * 128;
  const int z  = blockIdx.z;
  const ushort_t* Wt = (z == 0) ? Wqb : (z == 1) ? Wkb : Wvb;
  const int h = n0 >> 6;

  f32x4 acc[2][4];
  #pragma unroll
  for (int i = 0; i < 2; ++i)
    #pragma unroll
    for (int j = 0; j < 4; ++j) acc[i][j] = (f32x4){0.f, 0.f, 0.f, 0.f};

  const int srX = tid >> 1, scX = (tid & 1) * 32;
  const int srW = tid >> 2, scW = (tid & 3) * 16;

  for (int k0 = 0; k0 < E; k0 += 64) {
    uint4 x0 = *(const uint4*)(Xb + (size_t)(m0 + srX) * E + k0 + scX);
    uint4 x1 = *(const uint4*)(Xb + (size_t)(m0 + srX) * E + k0 + scX + 8);
    uint4 x2 = *(const uint4*)(Xb + (size_t)(m0 + srX) * E + k0 + scX + 16);
    uint4 x3 = *(const uint4*)(Xb + (size_t)(m0 + srX) * E + k0 + scX + 24);
    uint4 w0 = *(const uint4*)(Wt + (size_t)(n0 + srW) * E + k0 + scW);
    uint4 w1 = *(const uint4*)(Wt + (size_t)(n0 + srW) * E + k0 + scW + 8);
    *(uint4*)&Xs[swz(srX, scX)]      = x0;
    *(uint4*)&Xs[swz(srX, scX + 8)]  = x1;
    *(uint4*)&Xs[swz(srX, scX + 16)] = x2;
    *(uint4*)&Xs[swz(srX, scX + 24)] = x3;
    *(uint4*)&Ws[swz(srW, scW)]      = w0;
    *(uint4*)&Ws[swz(srW, scW + 8)]  = w1;
    __syncthreads();
    short8 a[2][2];
    #pragma unroll
    for (int mt = 0; mt < 2; ++mt)
      #pragma unroll
      for (int kh = 0; kh < 2; ++kh)
        a[mt][kh] = *(const short8*)&Xs[swz(wave * 32 + mt * 16 + l15, kh * 32 + quad * 8)];
    #pragma unroll
    for (int nt = 0; nt < 4; ++nt) {
      #pragma unroll
      for (int kh = 0; kh < 2; ++kh) {
        short8 bb = *(const short8*)&Ws[swz(nt * 16 + l15, kh * 32 + quad * 8)];
        #pragma unroll
        for (int mt = 0; mt < 2; ++mt)
          acc[mt][nt] = __builtin_amdgcn_mfma_f32_16x16x32_bf16(a[mt][kh], bb, acc[mt][nt], 0, 0, 0);
      }
    }
    __syncthreads();
  }

  const int b  = m0 >> 11;
  const int t0 = m0 & (T - 1);
  const int bh = b * H + h;
  const float qscale = (z == 0) ? 0.125f : 1.0f;

  if (z < 2) {
    #pragma unroll
    for (int mt = 0; mt < 2; ++mt) {
      #pragma unroll
      for (int r = 0; r < 4; ++r) {
        int mloc = wave * 32 + mt * 16 + quad * 4 + r;
        int t = (m0 + mloc) & (T - 1);
        float s0 = acc[mt][0][r] * qscale;
        float s1 = acc[mt][1][r] * qscale;
        float c0v = ct[t * 32 + l15],      sn0 = st[t * 32 + l15];
        float c1v = ct[t * 32 + 16 + l15], sn1 = st[t * 32 + 16 + l15];
        smem[swz(mloc, l15)]      = f2bf(s0 * c0v - s1 * sn0);
        smem[swz(mloc, 16 + l15)] = f2bf(s1 * c1v + s0 * sn1);
        smem[swz(mloc, 32 + l15)] = f2bf(acc[mt][2][r] * qscale);
        smem[swz(mloc, 48 + l15)] = f2bf(acc[mt][3][r] * qscale);
      }
    }
    __syncthreads();
    if (z == 0) {
      // Qf pieces: p = [qtl:8][kh:2][lane:64]
      #pragma unroll
      for (int i = 0; i < 4; ++i) {
        int p = tid + 256 * i;
        int qtl = p >> 7, kh = (p >> 6) & 1, ln = p & 63;
        int tl = qtl * 16 + (ln & 15);
        int d  = kh * 32 + (ln >> 4) * 8;
        uint4 v = *(const uint4*)&smem[swz(tl, d)];
        size_t off = ((size_t)((bh * 128 + (t0 >> 4) + qtl) * 2 + kh)) * 512 + ln * 8;
        *(uint4*)(qfb + off) = v;
      }
    } else {
      // Kf pieces: p = [ktl:2][mt:4][kh:2][lane:64]
      #pragma unroll
      for (int i = 0; i < 4; ++i) {
        int p = tid + 256 * i;
        int ktl = p >> 9, mt = (p >> 7) & 3, kh = (p >> 6) & 1, ln = p & 63;
        int tl = ktl * 64 + mt * 16 + (ln & 15);
        int d  = kh * 32 + (ln >> 4) * 8;
        uint4 v = *(const uint4*)&smem[swz(tl, d)];
        size_t off = ((size_t)(((bh * 32 + (t0 >> 6) + ktl) * 4 + mt) * 2 + kh)) * 512 + ln * 8;
        *(uint4*)(kfb + off) = v;
      }
    }
  } else {
    #pragma unroll
    for (int mt = 0; mt < 2; ++mt) {
      #pragma unroll
      for (int r = 0; r < 4; ++r) {
        int mloc = wave * 32 + mt * 16 + quad * 4 + r;
        int t = (m0 + mloc) & (T - 1);
        float s0 = acc[mt][0][r], s1 = acc[mt][1][r];
        float c0v = ct[t * 32 + l15],      sn0 = st[t * 32 + l15];
        float c1v = ct[t * 32 + 16 + l15], sn1 = st[t * 32 + 16 + l15];
        smem[(l15)      * 132 + mloc] = f2bf(s0 * c0v - s1 * sn0);
        smem[(16 + l15) * 132 + mloc] = f2bf(s1 * c1v + s0 * sn1);
        smem[(32 + l15) * 132 + mloc] = f2bf(acc[mt][2][r]);
        smem[(48 + l15) * 132 + mloc] = f2bf(acc[mt][3][r]);
      }
    }
    __syncthreads();
    // Vf pieces: p = [ktl:2][nt:4][kh:2][lane:64]
    #pragma unroll
    for (int i = 0; i < 4; ++i) {
      int p = tid + 256 * i;
      int ktl = p >> 9, nt = (p >> 7) & 3, kh = (p >> 6) & 1, ln = p & 63;
      int d  = nt * 16 + (ln & 15);
      int tl = ktl * 64 + kh * 32 + (ln >> 4) * 8;
      uint4 v = *(const uint4*)&smem[d * 132 + tl];
      size_t off = ((size_t)(((bh * 32 + (t0 >> 6) + ktl) * 4 + nt) * 2 + kh)) * 512 + ln * 8;
      *(uint4*)(vfb + off) = v;
    }
  }
}

// ---------------------------------------------------------------------------
// Flash attention, 2x2 wave split. Block = 64 q x bh (768 blocks); wave
// (wq,wk) computes S[kc = wk's 32][q = wq's 32] and partial O over its kc
// half. K/V fragments read DIRECTLY from fragment-order global (dup 2x,
// L1/L2-served). No K/V LDS, no in-loop barriers. Wave-private P quadrant in
// LDS (pad-40 rows). Static max; partial O/lsum combined by addition via one
// end-of-kernel LDS reduction (valid because no rescaling).
// ---------------------------------------------------------------------------
__global__ __launch_bounds__(256) void attn_kernel(
    const ushort_t* __restrict__ qfb, const ushort_t* __restrict__ kfb,
    const ushort_t* __restrict__ vfb, ushort_t* __restrict__ cbuf)
{
  __shared__ __align__(16) ushort_t Ps[4][32 * 40];   // per-wave P quadrant
  __shared__ __align__(16) float Osh[2][32][66];      // wk=0 partials, per wq
  __shared__ float Lsh[2][32];                        // wk=0 lsum partials
  const int tid  = threadIdx.x;
  const int wave = tid >> 6;
  const int wq = wave >> 1, wk = wave & 1;
  const int lane = tid & 63;
  const int l15  = lane & 15, quad = lane >> 4;
  const int q0 = blockIdx.x * 64;
  const int bh = blockIdx.y;
  const ushort_t* Qf = qfb + (size_t)bh * (T * HD);
  const ushort_t* Kf = kfb + (size_t)bh * (T * HD);
  const ushort_t* Vf = vfb + (size_t)bh * (T * HD);
  ushort_t* Pw = &Ps[wave][0];

  // Q B-frags for this wave's 32 q (2 groups of 16)
  short8 qa[2][2];
  #pragma unroll
  for (int qg = 0; qg < 2; ++qg)
    #pragma unroll
    for (int kh = 0; kh < 2; ++kh)
      qa[qg][kh] = *(const short8*)(Qf + ((size_t)(((q0 >> 4) + wq * 2 + qg) * 2 + kh)) * 512 + lane * 8);

  // tile-0 K/V frags (wave's kc half: mt in {2wk,2wk+1}; V kh = wk)
  short8 ka[2][2], va[4];
  #pragma unroll
  for (int i = 0; i < 2; ++i)
    #pragma unroll
    for (int kh = 0; kh < 2; ++kh)
      ka[i][kh] = *(const short8*)(Kf + ((size_t)((wk * 2 + i) * 2 + kh)) * 512 + lane * 8);
  #pragma unroll
  for (int nt = 0; nt < 4; ++nt)
    va[nt] = *(const short8*)(Vf + ((size_t)(nt * 2 + wk)) * 512 + lane * 8);

  f32x4 o[2][4];
  #pragma unroll
  for (int qg = 0; qg < 2; ++qg)
    #pragma unroll
    for (int nt = 0; nt < 4; ++nt) o[qg][nt] = (f32x4){0.f, 0.f, 0.f, 0.f};
  float lsum[2] = {0.f, 0.f};

  for (int kt = 0; kt < T / 64; ++kt) {
    // prefetch next tile's frags
    const int ktn = (kt + 1 < T / 64) ? kt + 1 : kt;
    short8 kn[2][2], vn[4];
    #pragma unroll
    for (int i = 0; i < 2; ++i)
      #pragma unroll
      for (int kh = 0; kh < 2; ++kh)
        kn[i][kh] = *(const short8*)(Kf + ((size_t)((ktn * 4 + wk * 2 + i) * 2 + kh)) * 512 + lane * 8);
    #pragma unroll
    for (int nt = 0; nt < 4; ++nt)
      vn[nt] = *(const short8*)(Vf + ((size_t)((ktn * 4 + nt) * 2 + wk)) * 512 + lane * 8);

    // S^T quadrant: ss[mt][qg] = C[kc16][q16]; row kc = quad*4+r, col q = l15
    f32x4 ss[2][2];
    #pragma unroll
    for (int mt = 0; mt < 2; ++mt)
      #pragma unroll
      for (int qg = 0; qg < 2; ++qg) {
        ss[mt][qg] = (f32x4){0.f, 0.f, 0.f, 0.f};
        ss[mt][qg] = __builtin_amdgcn_mfma_f32_16x16x32_bf16(ka[mt][0], qa[qg][0], ss[mt][qg], 0, 0, 0);
        ss[mt][qg] = __builtin_amdgcn_mfma_f32_16x16x32_bf16(ka[mt][1], qa[qg][1], ss[mt][qg], 0, 0, 0);
      }

    // exp + per-lane denominator (per qg) + packed P write into quadrant
    #pragma unroll
    for (int qg = 0; qg < 2; ++qg) {
      #pragma unroll
      for (int mt = 0; mt < 2; ++mt) {
        float p0 = __expf(ss[mt][qg][0]);
        float p1 = __expf(ss[mt][qg][1]);
        float p2 = __expf(ss[mt][qg][2]);
        float p3 = __expf(ss[mt][qg][3]);
        lsum[qg] += (p0 + p1) + (p2 + p3);
        uint2 w2;
        w2.x = pack_bf2(p0, p1);
        w2.y = pack_bf2(p2, p3);
        *(uint2*)&Pw[(qg * 16 + l15) * 40 + mt * 16 + quad * 4] = w2;
      }
    }

    // PV: A = P quadrant rows (q = l15 per group), k = wave's 32 kc
    short8 pa0 = *(const short8*)&Pw[(l15) * 40 + quad * 8];
    short8 pa1 = *(const short8*)&Pw[(16 + l15) * 40 + quad * 8];
    #pragma unroll
    for (int nt = 0; nt < 4; ++nt) {
      o[0][nt] = __builtin_amdgcn_mfma_f32_16x16x32_bf16(pa0, va[nt], o[0][nt], 0, 0, 0);
      o[1][nt] = __builtin_amdgcn_mfma_f32_16x16x32_bf16(pa1, va[nt], o[1][nt], 0, 0, 0);
    }

    #pragma unroll
    for (int i = 0; i < 2; ++i) {
      ka[i][0] = kn[i][0];
      ka[i][1] = kn[i][1];
    }
    #pragma unroll
    for (int nt = 0; nt < 4; ++nt) va[nt] = vn[nt];
  }

  // intra-wave lsum reduce over quads: lane -> total for q = qg*16 + l15
  #pragma unroll
  for (int qg = 0; qg < 2; ++qg) {
    lsum[qg] += __shfl_xor(lsum[qg], 16);
    lsum[qg] += __shfl_xor(lsum[qg], 32);
  }

  // cross-wk combine: wk=0 deposits partials, wk=1 adds + stores
  if (wk == 0) {
    #pragma unroll
    for (int qg = 0; qg < 2; ++qg)
      #pragma unroll
      for (int nt = 0; nt < 4; ++nt)
        #pragma unroll
        for (int r = 0; r < 4; ++r)
          Osh[wq][qg * 16 + quad * 4 + r][nt * 16 + l15] = o[qg][nt][r];
    if (lane < 16) {
      Lsh[wq][l15]      = lsum[0];
      Lsh[wq][16 + l15] = lsum[1];
    }
  }
  __syncthreads();
  if (wk == 1) {
    const int b = bh / H, h = bh % H;
    #pragma unroll
    for (int qg = 0; qg < 2; ++qg) {
      float ltot = lsum[qg] + Lsh[wq][qg * 16 + l15];
      float inv0 = 1.0f / ltot;
      #pragma unroll
      for (int r = 0; r < 4; ++r) {
        float inv = __shfl(inv0, quad * 4 + r);   // inv for q = qg*16+quad*4+r
        int t = q0 + wq * 32 + qg * 16 + quad * 4 + r;
        size_t base = ((size_t)b * T + t) * E + h * HD;
        #pragma unroll
        for (int nt = 0; nt < 4; ++nt) {
          float v = o[qg][nt][r] + Osh[wq][qg * 16 + quad * 4 + r][nt * 16 + l15];
          cbuf[base + nt * 16 + l15] = f2bf(v * inv);
        }
      }
    }
  }
}

// ---------------------------------------------------------------------------
// Output projection, 128x64 bf16 MFMA tile, K-step 64 (12 iters), fp32 + bias.
// ---------------------------------------------------------------------------
__global__ __launch_bounds__(256) void out_gemm(
    const ushort_t* __restrict__ Xc, const ushort_t* __restrict__ Wob,
    const float* __restrict__ bo, float* __restrict__ out)
{
  __shared__ __align__(16) ushort_t Xs[128 * 64];
  __shared__ __align__(16) ushort_t Ws[64 * 64];
  const int tid  = threadIdx.x;
  const int wave = tid >> 6;
  const int lane = tid & 63;
  const int l15  = lane & 15, quad = lane >> 4;
  const int n0 = blockIdx.x * 64;
  const int m0 = blockIdx.y * 128;

  f32x4 acc[2][4];
  #pragma unroll
  for (int i = 0; i < 2; ++i)
    #pragma unroll
    for (int j = 0; j < 4; ++j) acc[i][j] = (f32x4){0.f, 0.f, 0.f, 0.f};

  const int srX = tid >> 1, scX = (tid & 1) * 32;
  const int srW = tid >> 2, scW = (tid & 3) * 16;

  for (int k0 = 0; k0 < E; k0 += 64) {
    uint4 x0 = *(const uint4*)(Xc + (size_t)(m0 + srX) * E + k0 + scX);
    uint4 x1 = *(const uint4*)(Xc + (size_t)(m0 + srX) * E + k0 + scX + 8);
    uint4 x2 = *(const uint4*)(Xc + (size_t)(m0 + srX) * E + k0 + scX + 16);
    uint4 x3 = *(const uint4*)(Xc + (size_t)(m0 + srX) * E + k0 + scX + 24);
    uint4 w0 = *(const uint4*)(Wob + (size_t)(n0 + srW) * E + k0 + scW);
    uint4 w1 = *(const uint4*)(Wob + (size_t)(n0 + srW) * E + k0 + scW + 8);
    *(uint4*)&Xs[swz(srX, scX)]      = x0;
    *(uint4*)&Xs[swz(srX, scX + 8)]  = x1;
    *(uint4*)&Xs[swz(srX, scX + 16)] = x2;
    *(uint4*)&Xs[swz(srX, scX + 24)] = x3;
    *(uint4*)&Ws[swz(srW, scW)]      = w0;
    *(uint4*)&Ws[swz(srW, scW + 8)]  = w1;
    __syncthreads();
    short8 a[2][2];
    #pragma unroll
    for (int mt = 0; mt < 2; ++mt)
      #pragma unroll
      for (int kh = 0; kh < 2; ++kh)
        a[mt][kh] = *(const short8*)&Xs[swz(wave * 32 + mt * 16 + l15, kh * 32 + quad * 8)];
    #pragma unroll
    for (int nt = 0; nt < 4; ++nt) {
      #pragma unroll
      for (int kh = 0; kh < 2; ++kh) {
        short8 bb = *(const short8*)&Ws[swz(nt * 16 + l15, kh * 32 + quad * 8)];
        #pragma unroll
        for (int mt = 0; mt < 2; ++mt)
          acc[mt][nt] = __builtin_amdgcn_mfma_f32_16x16x32_bf16(a[mt][kh], bb, acc[mt][nt], 0, 0, 0);
      }
    }
    __syncthreads();
  }

  float bias[4];
  #pragma unroll
  for (int nt = 0; nt < 4; ++nt) bias[nt] = bo[n0 + nt * 16 + l15];
  #pragma unroll
  for (int mt = 0; mt < 2; ++mt) {
    #pragma unroll
    for (int r = 0; r < 4; ++r) {
      int m = m0 + wave * 32 + mt * 16 + quad * 4 + r;
      float* op = out + (size_t)m * E + n0;
      op[l15]      = acc[mt][0][r] + bias[0];
      op[16 + l15] = acc[mt][1][r] + bias[1];
      op[32 + l15] = acc[mt][2][r] + bias[2];
      op[48 + l15] = acc[mt][3][r] + bias[3];
    }
  }
}

// ---------------------------------------------------------------------------
extern "C" void kernel_launch(void* const* d_in, const int* in_sizes, int n_in,
                              void* d_out, int out_size, void* d_ws, size_t ws_size,
                              hipStream_t stream) {
  (void)in_sizes; (void)n_in; (void)out_size; (void)ws_size;
  const float* X    = (const float*)d_in[0];
  const float* rope = (const float*)d_in[1];
  const float* Wq   = (const float*)d_in[2];
  const float* Wk   = (const float*)d_in[3];
  const float* Wv   = (const float*)d_in[4];
  const float* Wo   = (const float*)d_in[5];
  const float* bo   = (const float*)d_in[6];
  float* out = (float*)d_out;

  const size_t NX = (size_t)B * T * E;
  const size_t NW = (size_t)E * E;
  const size_t NR = (size_t)T * 32;
  ushort_t* Xb  = (ushort_t*)d_ws;
  ushort_t* Wqb = Xb  + NX;
  ushort_t* Wkb = Wqb + NW;
  ushort_t* Wvb = Wkb + NW;
  ushort_t* Wob = Wvb + NW;
  ushort_t* qfb = Wob + NW;
  ushort_t* kfb = qfb + NX;
  ushort_t* vfb = kfb + NX;
  ushort_t* cb  = vfb + NX;
  float* ct = (float*)(cb + NX);
  float* st = ct + NR;

  const int total4 = (int)((NX + 4 * NW + NR) / 4);
  cvt_all<<<total4 / 256, 256, 0, stream>>>(X, Wq, Wk, Wv, Wo, rope,
                                            Xb, Wqb, Wkb, Wvb, Wob, ct, st);

  qkv_gemm<<<dim3(E / 64, (B * T) / 128, 3), 256, 0, stream>>>(
      Xb, Wqb, Wkb, Wvb, ct, st, qfb, kfb, vfb);
  attn_kernel<<<dim3(T / 64, B * H), 256, 0, stream>>>(qfb, kfb, vfb, cb);
  out_gemm<<<dim3(E / 64, (B * T) / 128), 256, 0, stream>>>(cb, Wob, bo, out);
}